// Round 4
// baseline (249.637 us; speedup 1.0000x reference)
//
#include <hip/hip_runtime.h>
#include <hip/hip_bf16.h>

#define NTOK   8192
#define TOPK   2
#define NEXP   8
#define KDIM   1024
#define NDIM   1024
#define MOUT   (NTOK * TOPK)        // 16384 dispatched rows
#define BM     128
#define BN     128
#define BK     64
#define MAXT   (MOUT / BM + NEXP)   // 136 tile slots (expert-boundary padding)
#define NBLK   (MAXT * (NDIM / BN)) // 1088 gemm blocks
#define CLSCAP (NBLK / 8)           // 136 positions per XCD class

// ws int-offset layout:
//   [64, 64+4*NBLK)     block table: {row0, rows, e, cy} per position
//   [8192, 8192+4096)   spill buffer (table build)
//   [16384, 32768)      row_token (16384 ints)  -> ends at byte 128K
// ws byte layout:
//   [128KiB, +16MiB)    x_bf16 [8192,1024]
//   [next,  +16MiB)     w_bf16 [8,1024,1024]
#define TBL      64
#define SPILL    8192
#define ROWTOK   16384
#define XB_OFF   (128 * 1024)
#define XB_BYTES (NTOK * KDIM * 2)
#define WB_OFF   (XB_OFF + XB_BYTES)
#define WB_BYTES (NEXP * NDIM * KDIM * 2)
#define WS_NEED  ((size_t)(WB_OFF + WB_BYTES))

typedef unsigned short ushort_t;
typedef __attribute__((ext_vector_type(8))) short short8;
typedef __attribute__((ext_vector_type(4))) float floatx4;
typedef __attribute__((address_space(1))) const unsigned int gu32;
typedef __attribute__((address_space(3))) unsigned int lu32;

// ---------------------------------------------------------------------------
// Table build (single thread): enumerate expert tiles x cy, place position
// p = idx*8 + e so p%8 == e (XCD round-robin pinning); consecutive idx within
// a class = the 8 cy-blocks of one slot (A-tile temporal locality on one XCD).
// ---------------------------------------------------------------------------
__device__ void build_table(const int* __restrict__ splits, int* __restrict__ ws) {
  for (int p = 0; p < NBLK; ++p) ws[TBL + 4 * p + 1] = 0;   // rows = 0
  int cnt[8];
#pragma unroll
  for (int e = 0; e < 8; ++e) cnt[e] = 0;
  int nspill = 0;
  int off = 0;
  for (int e = 0; e < NEXP; ++e) {
    int end = off + splits[e];
    for (int r0 = off; r0 < end; r0 += BM) {
      int rows = end - r0; if (rows > BM) rows = BM;
      for (int cy = 0; cy < NDIM / BN; ++cy) {
        if (cnt[e] < CLSCAP) {
          int p = (cnt[e]++) * 8 + e;
          ws[TBL + 4 * p + 0] = r0;  ws[TBL + 4 * p + 1] = rows;
          ws[TBL + 4 * p + 2] = e;   ws[TBL + 4 * p + 3] = cy;
        } else {
          ws[SPILL + 4 * nspill + 0] = r0;  ws[SPILL + 4 * nspill + 1] = rows;
          ws[SPILL + 4 * nspill + 2] = e;   ws[SPILL + 4 * nspill + 3] = cy;
          ++nspill;
        }
      }
    }
    off = end;
  }
  int e2 = 0;
  for (int s = 0; s < nspill; ++s) {        // total entries <= NBLK, always fits
    while (cnt[e2] >= CLSCAP) ++e2;
    int p = (cnt[e2]++) * 8 + e2;
    ws[TBL + 4 * p + 0] = ws[SPILL + 4 * s + 0];
    ws[TBL + 4 * p + 1] = ws[SPILL + 4 * s + 1];
    ws[TBL + 4 * p + 2] = ws[SPILL + 4 * s + 2];
    ws[TBL + 4 * p + 3] = ws[SPILL + 4 * s + 3];
  }
}

// ---------------------------------------------------------------------------
// Fused: scatter invert + table build + fp32->bf16 convert of x and W.
// Table build runs on one thread concurrently with the bulk converts.
// ---------------------------------------------------------------------------
__global__ __launch_bounds__(256)
void convert_setup(const float* __restrict__ x, const float* __restrict__ w,
                   const int* __restrict__ scatter, const int* __restrict__ splits,
                   ushort_t* __restrict__ xb, ushort_t* __restrict__ wb,
                   int* __restrict__ ws) {
  const int N4X = NTOK * KDIM / 4;
  const int N4W = NEXP * NDIM * KDIM / 4;
  int gtid = blockIdx.x * 256 + threadIdx.x;

  if (gtid < MOUT) {
    int s = scatter[gtid];          // flat slot gtid -> output row s
    ws[ROWTOK + s] = gtid / TOPK;   // token of that slot
  }
  if (gtid == 0) build_table(splits, ws);

  for (int i = gtid; i < N4X + N4W; i += gridDim.x * 256) {
    float4 v = (i < N4X) ? ((const float4*)x)[i] : ((const float4*)w)[i - N4X];
    union { __hip_bfloat162 h; unsigned int u; } lo, hi;
    lo.h = __float22bfloat162_rn(make_float2(v.x, v.y));
    hi.h = __float22bfloat162_rn(make_float2(v.z, v.w));
    uint2 u2; u2.x = lo.u; u2.y = hi.u;
    if (i < N4X) ((uint2*)xb)[i] = u2;
    else         ((uint2*)wb)[i - N4X] = u2;
  }
}

// ---------------------------------------------------------------------------
// Fast grouped GEMM: bf16 inputs, global_load_lds width-16 staging, inverse-
// swizzled fetch (LDS slot (r,p) holds global chunk p^(r&7); fragment reads
// use c^(m&7) -> conflict-free). 1-D grid over the XCD-placed block table.
// ---------------------------------------------------------------------------
__global__ __launch_bounds__(256, 3)
void moe_gemm_fast(const ushort_t* __restrict__ xb,   // [8192,1024] bf16
                   const ushort_t* __restrict__ wbm,  // [8,1024,1024] bf16
                   const int* __restrict__ ws,
                   float* __restrict__ out) {
  __shared__ ushort_t As[BM * BK];   // 16 KiB, swizzled row-major [128][64]
  __shared__ ushort_t Bs[BN * BK];   // 16 KiB

  int4 ent = ((const int4*)(ws + TBL))[blockIdx.x];
  const int rows = ent.y;
  if (rows == 0) return;
  const int row0 = ent.x;
  const int e    = ent.z;
  const int c0   = ent.w * BN;

  const int tid  = threadIdx.x;
  const int lane = tid & 63;
  const int wave = tid >> 6;
  const int wm   = (wave >> 1) * 64;
  const int wn   = (wave & 1) * 64;
  const int quad = lane >> 4;
  const int l16  = lane & 15;

  const int* __restrict__ row_token = ws + ROWTOK;

  // Staging: instr t stages 8 rows (wave*32+t*8 ..+7); lane -> row +lane/8.
  // HW puts lane at LDS pos lane&7; we fetch global chunk (lane&7)^(row&7).
  const int lrow8  = lane >> 3;
  const int gchunk = (lane & 7) ^ lrow8;

  const ushort_t* aptr[4];
  const ushort_t* bptr[4];
#pragma unroll
  for (int t = 0; t < 4; ++t) {
    int r  = wave * 32 + t * 8 + lrow8;
    int rc = (r < rows) ? r : (rows - 1);          // clamp tail to a valid row
    aptr[t] = xb + (size_t)row_token[row0 + rc] * KDIM + gchunk * 8;
    bptr[t] = wbm + ((size_t)e * NDIM + c0 + r) * KDIM + gchunk * 8;
  }

  floatx4 zero = {0.f, 0.f, 0.f, 0.f};
  floatx4 acc[4][4];
#pragma unroll
  for (int i = 0; i < 4; ++i)
#pragma unroll
    for (int j = 0; j < 4; ++j) acc[i][j] = zero;

#pragma unroll 4
  for (int kk = 0; kk < KDIM; kk += BK) {
#pragma unroll
    for (int t = 0; t < 4; ++t) {
      __builtin_amdgcn_global_load_lds(
          (gu32*)(const void*)(aptr[t] + kk),
          (lu32*)(void*)(As + (wave * 32 + t * 8) * BK), 16, 0, 0);
      __builtin_amdgcn_global_load_lds(
          (gu32*)(const void*)(bptr[t] + kk),
          (lu32*)(void*)(Bs + (wave * 32 + t * 8) * BK), 16, 0, 0);
    }
    __syncthreads();

#pragma unroll
    for (int k2 = 0; k2 < 2; ++k2) {
      short8 af[4], bf[4];
#pragma unroll
      for (int i = 0; i < 4; ++i) {
        int m = wm + i * 16 + l16;
        af[i] = *(const short8*)(&As[m * BK + (((k2 * 4 + quad) ^ (m & 7)) * 8)]);
      }
#pragma unroll
      for (int j = 0; j < 4; ++j) {
        int n = wn + j * 16 + l16;
        bf[j] = *(const short8*)(&Bs[n * BK + (((k2 * 4 + quad) ^ (n & 7)) * 8)]);
      }
#pragma unroll
      for (int i = 0; i < 4; ++i)
#pragma unroll
        for (int j = 0; j < 4; ++j)
          acc[i][j] = __builtin_amdgcn_mfma_f32_16x16x32_bf16(af[i], bf[j],
                                                              acc[i][j], 0, 0, 0);
    }
    __syncthreads();
  }

#pragma unroll
  for (int i = 0; i < 4; ++i) {
#pragma unroll
    for (int r = 0; r < 4; ++r) {
      int lrow = wm + i * 16 + quad * 4 + r;
      if (lrow < rows) {
        float* o = out + (size_t)(row0 + lrow) * NDIM + c0 + wn + l16;
#pragma unroll
        for (int j = 0; j < 4; ++j) o[j * 16] = acc[i][j][r];
      }
    }
  }
}

// ---------------------------------------------------------------------------
// Fallback path (ws too small for bf16 staging): setup-only kernel + fused
// in-loop convert GEMM over the same 1-D block table.
// ---------------------------------------------------------------------------
__global__ void setup_only(const int* __restrict__ scatter,
                           const int* __restrict__ splits,
                           int* __restrict__ ws) {
  int gtid = blockIdx.x * blockDim.x + threadIdx.x;
  if (gtid < MOUT) {
    int s = scatter[gtid];
    ws[ROWTOK + s] = gtid / TOPK;
  }
  if (gtid == 0) build_table(splits, ws);
}

__global__ __launch_bounds__(256)
void moe_gemm_fallback(const float* __restrict__ x,
                       const float* __restrict__ w,
                       const int* __restrict__ ws,
                       float* __restrict__ out) {
  __shared__ ushort_t As[BM * BK];
  __shared__ ushort_t Bs[BN * BK];

  int4 ent = ((const int4*)(ws + TBL))[blockIdx.x];
  const int rows = ent.y;
  if (rows == 0) return;
  const int row0 = ent.x;
  const int e    = ent.z;
  const int c0   = ent.w * BN;

  const int tid  = threadIdx.x;
  const int lane = tid & 63;
  const int wave = tid >> 6;
  const int wm   = (wave >> 1) * 64;
  const int wn   = (wave & 1) * 64;
  const int quad = lane >> 4;
  const int l16  = lane & 15;

  const int* __restrict__ row_token = ws + ROWTOK;

  const int f4    = tid & 15;
  const int rbase = tid >> 4;
  const int swz   = (f4 >> 1) ^ (rbase & 7);
  const int wroff = rbase * BK + swz * 8 + (f4 & 1) * 4;

  const float* __restrict__ wb = w + ((size_t)e * NDIM + c0) * KDIM;
  const float* pA[8];
#pragma unroll
  for (int i = 0; i < 8; ++i) {
    int r = rbase + i * 16;
    pA[i] = (r < rows) ? (x + (size_t)row_token[row0 + r] * KDIM + f4 * 4)
                       : nullptr;
  }
  const float* pB0 = wb + (size_t)rbase * KDIM + f4 * 4;

  floatx4 zero = {0.f, 0.f, 0.f, 0.f};
  floatx4 acc[4][4];
#pragma unroll
  for (int i = 0; i < 4; ++i)
#pragma unroll
    for (int j = 0; j < 4; ++j) acc[i][j] = zero;

#pragma unroll 1
  for (int kk = 0; kk < KDIM; kk += BK) {
#pragma unroll
    for (int i = 0; i < 8; ++i) {
      float4 v = {0.f, 0.f, 0.f, 0.f};
      if (pA[i]) v = *(const float4*)(pA[i] + kk);
      union { __hip_bfloat162 h; unsigned int u; } lo, hi;
      lo.h = __float22bfloat162_rn(make_float2(v.x, v.y));
      hi.h = __float22bfloat162_rn(make_float2(v.z, v.w));
      uint2 u2; u2.x = lo.u; u2.y = hi.u;
      *(uint2*)(&As[wroff + i * 16 * BK]) = u2;
    }
#pragma unroll
    for (int i = 0; i < 8; ++i) {
      float4 v = *(const float4*)(pB0 + (size_t)i * 16 * KDIM + kk);
      union { __hip_bfloat162 h; unsigned int u; } lo, hi;
      lo.h = __float22bfloat162_rn(make_float2(v.x, v.y));
      hi.h = __float22bfloat162_rn(make_float2(v.z, v.w));
      uint2 u2; u2.x = lo.u; u2.y = hi.u;
      *(uint2*)(&Bs[wroff + i * 16 * BK]) = u2;
    }
    __syncthreads();
#pragma unroll
    for (int k2 = 0; k2 < 2; ++k2) {
      short8 af[4], bf[4];
#pragma unroll
      for (int i = 0; i < 4; ++i) {
        int m = wm + i * 16 + l16;
        af[i] = *(const short8*)(&As[m * BK + ((k2 * 4 + quad) ^ (m & 7)) * 8]);
      }
#pragma unroll
      for (int j = 0; j < 4; ++j) {
        int n = wn + j * 16 + l16;
        bf[j] = *(const short8*)(&Bs[n * BK + ((k2 * 4 + quad) ^ (n & 7)) * 8]);
      }
#pragma unroll
      for (int i = 0; i < 4; ++i)
#pragma unroll
        for (int j = 0; j < 4; ++j)
          acc[i][j] = __builtin_amdgcn_mfma_f32_16x16x32_bf16(af[i], bf[j],
                                                              acc[i][j], 0, 0, 0);
    }
    __syncthreads();
  }

#pragma unroll
  for (int i = 0; i < 4; ++i) {
#pragma unroll
    for (int r = 0; r < 4; ++r) {
      int lrow = wm + i * 16 + quad * 4 + r;
      if (lrow < rows) {
        float* o = out + (size_t)(row0 + lrow) * NDIM + c0 + wn + l16;
#pragma unroll
        for (int j = 0; j < 4; ++j) o[j * 16] = acc[i][j][r];
      }
    }
  }
}

// ---------------------------------------------------------------------------
extern "C" void kernel_launch(void* const* d_in, const int* in_sizes, int n_in,
                              void* d_out, int out_size, void* d_ws, size_t ws_size,
                              hipStream_t stream) {
  const float* x       = (const float*)d_in[0];   // [8192,1024] f32
  const float* weights = (const float*)d_in[1];   // [8,1024,1024] f32
  const int*   scatter = (const int*)d_in[2];     // [8192,2] i32
  const int*   splits  = (const int*)d_in[3];     // [8] i32
  float*       out     = (float*)d_out;           // [16384,1024] f32
  int*         ws      = (int*)d_ws;

  if (ws_size >= WS_NEED) {
    ushort_t* xb = (ushort_t*)((char*)d_ws + XB_OFF);
    ushort_t* wb = (ushort_t*)((char*)d_ws + WB_OFF);
    convert_setup<<<dim3(2048), dim3(256), 0, stream>>>(x, weights, scatter,
                                                        splits, xb, wb, ws);
    moe_gemm_fast<<<dim3(NBLK), dim3(256), 0, stream>>>(xb, wb, ws, out);
  } else {
    setup_only<<<dim3(MOUT / 256), dim3(256), 0, stream>>>(scatter, splits, ws);
    moe_gemm_fallback<<<dim3(NBLK), dim3(256), 0, stream>>>(x, weights, ws, out);
  }
}

// Round 5
// 154.787 us; speedup vs baseline: 1.6128x; 1.6128x over previous
//
#include <hip/hip_runtime.h>
#include <hip/hip_bf16.h>

#define NTOK   8192
#define TOPK   2
#define NEXP   8
#define KDIM   1024
#define NDIM   1024
#define MOUT   (NTOK * TOPK)        // 16384 dispatched rows
#define BM     128
#define BN     128
#define BK     64
#define MAXT   (MOUT / BM + NEXP)   // 136 tile slots (expert-boundary padding)
#define NBLK   (MAXT * (NDIM / BN)) // 1088 gemm blocks
#define CLSCAP (NBLK / 8)           // 136 positions per XCD class

// ws int-offset layout:
//   [16384, 32768)      row_token (16384 ints)  -> ends at byte 128K
// ws byte layout:
//   [128KiB, +16MiB)    x_bf16 [8192,1024]
//   [next,  +16MiB)     w_bf16 [8,1024,1024]
#define ROWTOK   16384
#define XB_OFF   (128 * 1024)
#define XB_BYTES (NTOK * KDIM * 2)
#define WB_OFF   (XB_OFF + XB_BYTES)
#define WB_BYTES (NEXP * NDIM * KDIM * 2)
#define WS_NEED  ((size_t)(WB_OFF + WB_BYTES))

typedef unsigned short ushort_t;
typedef __attribute__((ext_vector_type(8))) short short8;
typedef __attribute__((ext_vector_type(4))) float floatx4;
typedef __attribute__((address_space(1))) const unsigned int gu32;
typedef __attribute__((address_space(3))) unsigned int lu32;

// ---------------------------------------------------------------------------
// Analytic block -> (row0, rows, e, cy) mapping (XCD-aware placement).
// Position b: class c = b%8 (round-robin XCD), in-class index i = b/8.
// Expert e's entry list L_e = its tiles x 8 cy's (tile-major). Class e takes
// min(|L_e|, CLSCAP) of L_e; remainders spill into leftover class capacity in
// class order. ~60 uniform scalar ops per block; no device table needed.
// Returns rows=0 for idle positions.
// ---------------------------------------------------------------------------
__device__ __forceinline__ void map_block(int b, const int* __restrict__ splits,
                                          int& row0, int& rows, int& e_out,
                                          int& cy) {
  int sp[8], off[8], n[8], take[8];
  int o = 0;
#pragma unroll
  for (int e = 0; e < 8; ++e) {
    sp[e] = splits[e];
    off[e] = o;
    o += sp[e];
    int tiles = (sp[e] + BM - 1) / BM;
    n[e] = 8 * tiles;
    take[e] = (n[e] < CLSCAP) ? n[e] : CLSCAP;
  }
  const int c = b & 7, i = b >> 3;
  int e = -1, j = 0;
  if (i < take[c]) {
    e = c; j = i;
  } else {
    int freeBefore = 0;
#pragma unroll
    for (int cc = 0; cc < 8; ++cc)
      if (cc < c) freeBefore += CLSCAP - take[cc];
    int spos = freeBefore + (i - take[c]);
    int acc = 0;
#pragma unroll
    for (int ee = 0; ee < 8; ++ee) {
      int sp_e = n[ee] - take[ee];
      if (e < 0 && spos < acc + sp_e) { e = ee; j = CLSCAP + (spos - acc); }
      acc += sp_e;
    }
    if (e < 0) { rows = 0; return; }   // idle position
  }
  int t = j >> 3;
  cy = j & 7;
  row0 = off[e] + t * BM;
  int rem = off[e] + sp[e] - row0;
  rows = (rem > BM) ? BM : rem;
  if (rows < 0) rows = 0;
  e_out = e;
}

// ---------------------------------------------------------------------------
// Fully-parallel setup: scatter invert + fp32->bf16 convert of x and W.
// ---------------------------------------------------------------------------
__global__ __launch_bounds__(256)
void convert_setup(const float* __restrict__ x, const float* __restrict__ w,
                   const int* __restrict__ scatter,
                   ushort_t* __restrict__ xb, ushort_t* __restrict__ wb,
                   int* __restrict__ ws) {
  const int N4X = NTOK * KDIM / 4;
  const int N4W = NEXP * NDIM * KDIM / 4;
  int gtid = blockIdx.x * 256 + threadIdx.x;

  if (gtid < MOUT) {
    int s = scatter[gtid];          // flat slot gtid -> output row s
    ws[ROWTOK + s] = gtid / TOPK;   // token of that slot
  }

  for (int i = gtid; i < N4X + N4W; i += gridDim.x * 256) {
    float4 v = (i < N4X) ? ((const float4*)x)[i] : ((const float4*)w)[i - N4X];
    union { __hip_bfloat162 h; unsigned int u; } lo, hi;
    lo.h = __float22bfloat162_rn(make_float2(v.x, v.y));
    hi.h = __float22bfloat162_rn(make_float2(v.z, v.w));
    uint2 u2; u2.x = lo.u; u2.y = hi.u;
    if (i < N4X) ((uint2*)xb)[i] = u2;
    else         ((uint2*)wb)[i - N4X] = u2;
  }
}

// ---------------------------------------------------------------------------
// Fast grouped GEMM: bf16 inputs, global_load_lds width-16 staging, inverse-
// swizzled fetch (LDS slot (r,p) holds global chunk p^(r&7); fragment reads
// use c^(m&7) -> conflict-free). Analytic XCD-aware block mapping.
// ---------------------------------------------------------------------------
__global__ __launch_bounds__(256, 3)
void moe_gemm_fast(const ushort_t* __restrict__ xb,   // [8192,1024] bf16
                   const ushort_t* __restrict__ wbm,  // [8,1024,1024] bf16
                   const int* __restrict__ splits,
                   const int* __restrict__ ws,
                   float* __restrict__ out) {
  __shared__ ushort_t As[BM * BK];   // 16 KiB, swizzled row-major [128][64]
  __shared__ ushort_t Bs[BN * BK];   // 16 KiB

  int row0, rows, e, cyi;
  map_block(blockIdx.x, splits, row0, rows, e, cyi);
  if (rows == 0) return;
  const int c0 = cyi * BN;

  const int tid  = threadIdx.x;
  const int lane = tid & 63;
  const int wave = tid >> 6;
  const int wm   = (wave >> 1) * 64;
  const int wn   = (wave & 1) * 64;
  const int quad = lane >> 4;
  const int l16  = lane & 15;

  const int* __restrict__ row_token = ws + ROWTOK;

  // Staging: instr t stages 8 rows (wave*32+t*8 ..+7); lane -> row +lane/8.
  // HW puts lane at LDS pos lane&7; we fetch global chunk (lane&7)^(row&7).
  const int lrow8  = lane >> 3;
  const int gchunk = (lane & 7) ^ lrow8;

  const ushort_t* aptr[4];
  const ushort_t* bptr[4];
#pragma unroll
  for (int t = 0; t < 4; ++t) {
    int r  = wave * 32 + t * 8 + lrow8;
    int rc = (r < rows) ? r : (rows - 1);          // clamp tail to a valid row
    aptr[t] = xb + (size_t)row_token[row0 + rc] * KDIM + gchunk * 8;
    bptr[t] = wbm + ((size_t)e * NDIM + c0 + r) * KDIM + gchunk * 8;
  }

  floatx4 zero = {0.f, 0.f, 0.f, 0.f};
  floatx4 acc[4][4];
#pragma unroll
  for (int i = 0; i < 4; ++i)
#pragma unroll
    for (int j = 0; j < 4; ++j) acc[i][j] = zero;

#pragma unroll 4
  for (int kk = 0; kk < KDIM; kk += BK) {
#pragma unroll
    for (int t = 0; t < 4; ++t) {
      __builtin_amdgcn_global_load_lds(
          (gu32*)(const void*)(aptr[t] + kk),
          (lu32*)(void*)(As + (wave * 32 + t * 8) * BK), 16, 0, 0);
      __builtin_amdgcn_global_load_lds(
          (gu32*)(const void*)(bptr[t] + kk),
          (lu32*)(void*)(Bs + (wave * 32 + t * 8) * BK), 16, 0, 0);
    }
    __syncthreads();

#pragma unroll
    for (int k2 = 0; k2 < 2; ++k2) {
      short8 af[4], bf[4];
#pragma unroll
      for (int i = 0; i < 4; ++i) {
        int m = wm + i * 16 + l16;
        af[i] = *(const short8*)(&As[m * BK + (((k2 * 4 + quad) ^ (m & 7)) * 8)]);
      }
#pragma unroll
      for (int j = 0; j < 4; ++j) {
        int n = wn + j * 16 + l16;
        bf[j] = *(const short8*)(&Bs[n * BK + (((k2 * 4 + quad) ^ (n & 7)) * 8)]);
      }
#pragma unroll
      for (int i = 0; i < 4; ++i)
#pragma unroll
        for (int j = 0; j < 4; ++j)
          acc[i][j] = __builtin_amdgcn_mfma_f32_16x16x32_bf16(af[i], bf[j],
                                                              acc[i][j], 0, 0, 0);
    }
    __syncthreads();
  }

#pragma unroll
  for (int i = 0; i < 4; ++i) {
#pragma unroll
    for (int r = 0; r < 4; ++r) {
      int lrow = wm + i * 16 + quad * 4 + r;
      if (lrow < rows) {
        float* o = out + (size_t)(row0 + lrow) * NDIM + c0 + wn + l16;
#pragma unroll
        for (int j = 0; j < 4; ++j) o[j * 16] = acc[i][j][r];
      }
    }
  }
}

// ---------------------------------------------------------------------------
// Fallback path (ws too small for bf16 staging): scatter-invert kernel +
// fused in-loop convert GEMM with the same analytic mapping.
// ---------------------------------------------------------------------------
__global__ void setup_only(const int* __restrict__ scatter,
                           int* __restrict__ ws) {
  int gtid = blockIdx.x * blockDim.x + threadIdx.x;
  if (gtid < MOUT) {
    int s = scatter[gtid];
    ws[ROWTOK + s] = gtid / TOPK;
  }
}

__global__ __launch_bounds__(256)
void moe_gemm_fallback(const float* __restrict__ x,
                       const float* __restrict__ w,
                       const int* __restrict__ splits,
                       const int* __restrict__ ws,
                       float* __restrict__ out) {
  __shared__ ushort_t As[BM * BK];
  __shared__ ushort_t Bs[BN * BK];

  int row0, rows, e, cyi;
  map_block(blockIdx.x, splits, row0, rows, e, cyi);
  if (rows == 0) return;
  const int c0 = cyi * BN;

  const int tid  = threadIdx.x;
  const int lane = tid & 63;
  const int wave = tid >> 6;
  const int wm   = (wave >> 1) * 64;
  const int wn   = (wave & 1) * 64;
  const int quad = lane >> 4;
  const int l16  = lane & 15;

  const int* __restrict__ row_token = ws + ROWTOK;

  const int f4    = tid & 15;
  const int rbase = tid >> 4;
  const int swz   = (f4 >> 1) ^ (rbase & 7);
  const int wroff = rbase * BK + swz * 8 + (f4 & 1) * 4;

  const float* __restrict__ wb = w + ((size_t)e * NDIM + c0) * KDIM;
  const float* pA[8];
#pragma unroll
  for (int i = 0; i < 8; ++i) {
    int r = rbase + i * 16;
    pA[i] = (r < rows) ? (x + (size_t)row_token[row0 + r] * KDIM + f4 * 4)
                       : nullptr;
  }
  const float* pB0 = wb + (size_t)rbase * KDIM + f4 * 4;

  floatx4 zero = {0.f, 0.f, 0.f, 0.f};
  floatx4 acc[4][4];
#pragma unroll
  for (int i = 0; i < 4; ++i)
#pragma unroll
    for (int j = 0; j < 4; ++j) acc[i][j] = zero;

#pragma unroll 1
  for (int kk = 0; kk < KDIM; kk += BK) {
#pragma unroll
    for (int i = 0; i < 8; ++i) {
      float4 v = {0.f, 0.f, 0.f, 0.f};
      if (pA[i]) v = *(const float4*)(pA[i] + kk);
      union { __hip_bfloat162 h; unsigned int u; } lo, hi;
      lo.h = __float22bfloat162_rn(make_float2(v.x, v.y));
      hi.h = __float22bfloat162_rn(make_float2(v.z, v.w));
      uint2 u2; u2.x = lo.u; u2.y = hi.u;
      *(uint2*)(&As[wroff + i * 16 * BK]) = u2;
    }
#pragma unroll
    for (int i = 0; i < 8; ++i) {
      float4 v = *(const float4*)(pB0 + (size_t)i * 16 * KDIM + kk);
      union { __hip_bfloat162 h; unsigned int u; } lo, hi;
      lo.h = __float22bfloat162_rn(make_float2(v.x, v.y));
      hi.h = __float22bfloat162_rn(make_float2(v.z, v.w));
      uint2 u2; u2.x = lo.u; u2.y = hi.u;
      *(uint2*)(&Bs[wroff + i * 16 * BK]) = u2;
    }
    __syncthreads();
#pragma unroll
    for (int k2 = 0; k2 < 2; ++k2) {
      short8 af[4], bf[4];
#pragma unroll
      for (int i = 0; i < 4; ++i) {
        int m = wm + i * 16 + l16;
        af[i] = *(const short8*)(&As[m * BK + ((k2 * 4 + quad) ^ (m & 7)) * 8]);
      }
#pragma unroll
      for (int j = 0; j < 4; ++j) {
        int n = wn + j * 16 + l16;
        bf[j] = *(const short8*)(&Bs[n * BK + ((k2 * 4 + quad) ^ (n & 7)) * 8]);
      }
#pragma unroll
      for (int i = 0; i < 4; ++i)
#pragma unroll
        for (int j = 0; j < 4; ++j)
          acc[i][j] = __builtin_amdgcn_mfma_f32_16x16x32_bf16(af[i], bf[j],
                                                              acc[i][j], 0, 0, 0);
    }
    __syncthreads();
  }

#pragma unroll
  for (int i = 0; i < 4; ++i) {
#pragma unroll
    for (int r = 0; r < 4; ++r) {
      int lrow = wm + i * 16 + quad * 4 + r;
      if (lrow < rows) {
        float* o = out + (size_t)(row0 + lrow) * NDIM + c0 + wn + l16;
#pragma unroll
        for (int j = 0; j < 4; ++j) o[j * 16] = acc[i][j][r];
      }
    }
  }
}

// ---------------------------------------------------------------------------
extern "C" void kernel_launch(void* const* d_in, const int* in_sizes, int n_in,
                              void* d_out, int out_size, void* d_ws, size_t ws_size,
                              hipStream_t stream) {
  const float* x       = (const float*)d_in[0];   // [8192,1024] f32
  const float* weights = (const float*)d_in[1];   // [8,1024,1024] f32
  const int*   scatter = (const int*)d_in[2];     // [8192,2] i32
  const int*   splits  = (const int*)d_in[3];     // [8] i32
  float*       out     = (float*)d_out;           // [16384,1024] f32
  int*         ws      = (int*)d_ws;

  if (ws_size >= WS_NEED) {
    ushort_t* xb = (ushort_t*)((char*)d_ws + XB_OFF);
    ushort_t* wb = (ushort_t*)((char*)d_ws + WB_OFF);
    convert_setup<<<dim3(2048), dim3(256), 0, stream>>>(x, weights, scatter,
                                                        xb, wb, ws);
    moe_gemm_fast<<<dim3(NBLK), dim3(256), 0, stream>>>(xb, wb, splits, ws, out);
  } else {
    setup_only<<<dim3(MOUT / 256), dim3(256), 0, stream>>>(scatter, ws);
    moe_gemm_fallback<<<dim3(NBLK), dim3(256), 0, stream>>>(x, weights, splits,
                                                            ws, out);
  }
}